// Round 2
// baseline (171.426 us; speedup 1.0000x reference)
//
#include <hip/hip_runtime.h>
#include <math.h>

// MovingMaxMinHorizontal: streaming causal max-filter(L=64) then min-filter(L=64)
// over [B=64, C=64, T=4096] f32 rows, with prev_input (-inf) / prev_max_out (+inf)
// state padding of length L-1=63 on the left.
//
// out[t] = min_{j in [t..t+63]} mid_padded[j],  mid_padded = [prev_max_out, mid]
// mid[t] = max_{j in [t..t+63]} in_padded[j],   in_padded  = [prev_input,  x]
//
// One block per row. Padded row staged in LDS; window L == wavefront 64 lets us
// compute 64 outputs per wave with one suffix-scan + one exclusive prefix-scan
// (log2(64)=6 shuffle steps each).

#define TT   4096
#define LF   64
#define PADN (LF - 1)        // 63
#define PLEN (TT + PADN)     // 4159

__global__ __launch_bounds__(512)
void mmh_kernel(const float* __restrict__ x,
                const float* __restrict__ prev_input,
                const float* __restrict__ prev_max_out,
                float* __restrict__ out)
{
    // logical padded index p lives at s[p + 1] so the x-portion (p>=63 -> idx>=64)
    // is 16B-aligned for float4 LDS writes. +2 tail pad covers the clamped read.
    __shared__ float s_in[PLEN + 2];
    __shared__ float s_mid[PLEN + 2];

    const int row   = blockIdx.x;       // 0 .. B*C-1
    const int tid   = threadIdx.x;
    const int lane  = tid & 63;
    const int wave  = tid >> 6;
    const int nwv   = blockDim.x >> 6;  // 8

    const float* xrow  = x            + (size_t)row * TT;
    const float* pirow = prev_input   + (size_t)row * PADN;
    const float* pmrow = prev_max_out + (size_t)row * PADN;
    float*       orow  = out          + (size_t)row * TT;

    // ---- stage 0: load padded row into LDS (x once, coalesced float4) ----
    for (int i = tid; i < TT / 4; i += blockDim.x) {
        float4 v = reinterpret_cast<const float4*>(xrow)[i];
        *reinterpret_cast<float4*>(&s_in[64 + 4 * i]) = v;
    }
    if (tid < PADN) {
        s_in[1 + tid]  = pirow[tid];
        s_mid[1 + tid] = pmrow[tid];
    }
    __syncthreads();

    // ---- stage 1: sliding max over in_padded -> s_mid[64..4159] ----
    for (int c = wave; c < TT / LF; c += nwv) {
        const int base = c * LF;
        float a0 = s_in[1 + base + lane];
        int   i1 = base + LF + lane;                  // up to 4159 on last chunk
        float a1 = s_in[1 + (i1 > PLEN - 1 ? PLEN - 1 : i1)];  // clamped dup; unused lane

        // suffix max: s[l] = max(a0[l..63])   (OOB shfl_down returns own value; max idempotent)
        float s = a0;
        #pragma unroll
        for (int d = 1; d < 64; d <<= 1)
            s = fmaxf(s, __shfl_down(s, d, 64));

        // inclusive prefix max of a1, then shift to exclusive
        float p = a1;
        #pragma unroll
        for (int d = 1; d < 64; d <<= 1)
            p = fmaxf(p, __shfl_up(p, d, 64));
        float pe = __shfl_up(p, 1, 64);
        if (lane == 0) pe = -INFINITY;

        s_mid[64 + base + lane] = fmaxf(s, pe);
    }
    __syncthreads();

    // ---- stage 2: sliding min over mid_padded -> out ----
    for (int c = wave; c < TT / LF; c += nwv) {
        const int base = c * LF;
        float a0 = s_mid[1 + base + lane];
        int   i1 = base + LF + lane;
        float a1 = s_mid[1 + (i1 > PLEN - 1 ? PLEN - 1 : i1)];

        float s = a0;
        #pragma unroll
        for (int d = 1; d < 64; d <<= 1)
            s = fminf(s, __shfl_down(s, d, 64));

        float p = a1;
        #pragma unroll
        for (int d = 1; d < 64; d <<= 1)
            p = fminf(p, __shfl_up(p, d, 64));
        float pe = __shfl_up(p, 1, 64);
        if (lane == 0) pe = INFINITY;

        orow[base + lane] = fminf(s, pe);
    }
}

extern "C" void kernel_launch(void* const* d_in, const int* in_sizes, int n_in,
                              void* d_out, int out_size, void* d_ws, size_t ws_size,
                              hipStream_t stream) {
    const float* x            = (const float*)d_in[0];  // [64,64,4096]
    const float* prev_input   = (const float*)d_in[1];  // [64,64,63]
    const float* prev_max_out = (const float*)d_in[2];  // [64,64,63]
    float*       out          = (float*)d_out;          // [64,64,4096]

    const int rows = 64 * 64;
    mmh_kernel<<<rows, 512, 0, stream>>>(x, prev_input, prev_max_out, out);
}

// Round 6
// 130.053 us; speedup vs baseline: 1.3181x; 1.3181x over previous
//
#include <hip/hip_runtime.h>
#include <math.h>

// MovingMaxMinHorizontal: causal max-filter(L=64) then min-filter(L=64) over
// [B=64, C=64, T=4096] f32 rows with -inf / +inf streaming-state left pads.
//
// Structure: window L == wave width 64. Per 64-output chunk:
//   out[t] = op( suffix_scan(a0)[t], excl_prefix_scan(a1)[t] ),  a0/a1 = two
// consecutive 64-elem slabs. Scans are DPP-based (VALU pipe, no ds_bpermute):
//   - suffix scan  = inclusive scan of REVERSED input (LDS read at 63-lane),
//     un-reversed afterwards with a single ds_bpermute.
//   - exclusive prefix = inclusive scan of input read at index-1 with lane0
//     forced to the identity — no cross-lane shift needed.
// Inclusive wave64 scan = 6 DPP steps: row_shr 1,2,4,8; row_bcast:15 (rm 0xA);
// row_bcast:31 (rm 0xC). Invalid lanes keep `old` = own value (idempotent for
// max/min). DS ops per chunk drop 16 -> 4 vs the shuffle version.

#define TT   4096
#define LF   64
#define PADN (LF - 1)        // 63
#define PLEN (TT + PADN)     // 4159

// update_dpp: old = v so masked/invalid lanes are a no-op under max/min.
#define DPP_UPD(v, ctrl, rmask) \
  __int_as_float(__builtin_amdgcn_update_dpp(__float_as_int(v), __float_as_int(v), ctrl, rmask, 0xF, false))

#define SCAN_MAX(p) do { \
  p = fmaxf(p, DPP_UPD(p, 0x111, 0xF)); \
  p = fmaxf(p, DPP_UPD(p, 0x112, 0xF)); \
  p = fmaxf(p, DPP_UPD(p, 0x114, 0xF)); \
  p = fmaxf(p, DPP_UPD(p, 0x118, 0xF)); \
  p = fmaxf(p, DPP_UPD(p, 0x142, 0xA)); \
  p = fmaxf(p, DPP_UPD(p, 0x143, 0xC)); \
} while (0)

#define SCAN_MIN(p) do { \
  p = fminf(p, DPP_UPD(p, 0x111, 0xF)); \
  p = fminf(p, DPP_UPD(p, 0x112, 0xF)); \
  p = fminf(p, DPP_UPD(p, 0x114, 0xF)); \
  p = fminf(p, DPP_UPD(p, 0x118, 0xF)); \
  p = fminf(p, DPP_UPD(p, 0x142, 0xA)); \
  p = fminf(p, DPP_UPD(p, 0x143, 0xC)); \
} while (0)

__global__ __launch_bounds__(512)
void mmh_kernel(const float* __restrict__ x,
                const float* __restrict__ prev_input,
                const float* __restrict__ prev_max_out,
                float* __restrict__ out)
{
    // padded index p lives at s[p+1] so the x portion (idx>=64) is 16B-aligned.
    __shared__ float s_in[PLEN + 2];
    __shared__ float s_mid[PLEN + 2];

    const int row  = blockIdx.x;
    const int tid  = threadIdx.x;
    const int lane = tid & 63;
    const int wave = tid >> 6;          // 0..7

    const float* xrow  = x            + (size_t)row * TT;
    const float* pirow = prev_input   + (size_t)row * PADN;
    const float* pmrow = prev_max_out + (size_t)row * PADN;
    float*       orow  = out          + (size_t)row * TT;

    const int rev4 = (63 - lane) << 2;  // bpermute byte addr for lane reversal

    // ---- stage 0: row -> LDS (coalesced float4) + state pads ----
    for (int i = tid; i < TT / 4; i += blockDim.x) {
        float4 v = reinterpret_cast<const float4*>(xrow)[i];
        *reinterpret_cast<float4*>(&s_in[64 + 4 * i]) = v;
    }
    if (tid < PADN) {
        s_in[1 + tid]  = pirow[tid];
        s_mid[1 + tid] = pmrow[tid];
    }
    __syncthreads();

    // ---- stage 1: sliding max over in_padded -> s_mid[64..4159] ----
    #pragma unroll
    for (int cc = 0; cc < 8; ++cc) {
        const int base = wave * 512 + cc * 64;
        float a0r = s_in[1 + base + 63 - lane];      // reversed slab 0
        float a1e = s_in[base + 64 + lane];          // slab 1 shifted by -1
        if (lane == 0) a1e = -INFINITY;
        SCAN_MAX(a0r);                                // -> prefix of reversed = suffix
        SCAN_MAX(a1e);                                // -> exclusive prefix of slab 1
        float sfx = __int_as_float(
            __builtin_amdgcn_ds_bpermute(rev4, __float_as_int(a0r)));
        s_mid[64 + base + lane] = fmaxf(sfx, a1e);
    }
    __syncthreads();

    // ---- stage 2: sliding min over mid_padded -> out ----
    #pragma unroll
    for (int cc = 0; cc < 8; ++cc) {
        const int base = wave * 512 + cc * 64;
        float a0r = s_mid[1 + base + 63 - lane];
        float a1e = s_mid[base + 64 + lane];
        if (lane == 0) a1e = INFINITY;
        SCAN_MIN(a0r);
        SCAN_MIN(a1e);
        float sfx = __int_as_float(
            __builtin_amdgcn_ds_bpermute(rev4, __float_as_int(a0r)));
        orow[base + lane] = fminf(sfx, a1e);
    }
}

extern "C" void kernel_launch(void* const* d_in, const int* in_sizes, int n_in,
                              void* d_out, int out_size, void* d_ws, size_t ws_size,
                              hipStream_t stream) {
    const float* x            = (const float*)d_in[0];  // [64,64,4096]
    const float* prev_input   = (const float*)d_in[1];  // [64,64,63]
    const float* prev_max_out = (const float*)d_in[2];  // [64,64,63]
    float*       out          = (float*)d_out;          // [64,64,4096]

    mmh_kernel<<<64 * 64, 512, 0, stream>>>(x, prev_input, prev_max_out, out);
}

// Round 7
// 116.470 us; speedup vs baseline: 1.4718x; 1.1166x over previous
//
#include <hip/hip_runtime.h>
#include <math.h>

// MovingMaxMinHorizontal: causal max-filter(L=64) then min-filter(L=64) over
// [B=64, C=64, T=4096] f32 rows with -inf / +inf streaming-state left pads.
//
// Round-7 structure: 256 outputs per wave-chunk, 4 elems/lane, one 64-slab per
// 16-lane DPP row (4 slabs scanned concurrently per instruction).
// out[t] (t = 64s + j) = OP( suffix_j(slab_s), excl_prefix_j(slab_{s+1}) ):
//   - within-lane serial scans (3 ops), row scans of lane totals via DPP
//     row_shl/row_shr 1,2,4,8 (4-step chains, suffix & prefix independent),
//   - exclusive shift with identity via update_dpp(old=ID, ...).
// pad[p] stored at s[p] so slabs are 64-elem (16B×4) aligned -> all LDS
// traffic is conflict-free b128. Stage-1 writeback realigned in-register:
// w3 = update_dpp(old=u, src=r0, row_shl:1)  (u = a1-slab running total; at
// row-boundary lanes the needed value IS the a1-slab max).

#define TT   4096
#define PADN 63
#define SLEN 4160   // pad[0..4158] + 1 spare identity slot

template<int CTRL>
__device__ __forceinline__ float dpp_self(float v) {
  return __int_as_float(__builtin_amdgcn_update_dpp(
      __float_as_int(v), __float_as_int(v), CTRL, 0xF, 0xF, false));
}
template<int CTRL>
__device__ __forceinline__ float dpp_old(float oldv, float v) {
  return __int_as_float(__builtin_amdgcn_update_dpp(
      __float_as_int(oldv), __float_as_int(v), CTRL, 0xF, 0xF, false));
}

// For the 256-output chunk at slab-aligned base b: this lane's 4 window
// results r[0..3], plus u = inclusive row-prefix of a1 lane-totals (lane 15
// of each row holds the full a1-slab reduction).
template<bool IS_MAX>
__device__ __forceinline__ void chunk_windows(const float* sbuf, int b, int lane,
                                              float r[4], float& u_out) {
  const float ID = IS_MAX ? -INFINITY : INFINITY;
#define OPF(x, y) (IS_MAX ? fmaxf((x), (y)) : fminf((x), (y)))
  const float4 a0 = *reinterpret_cast<const float4*>(sbuf + b + 4 * lane);
  const float4 a1 = *reinterpret_cast<const float4*>(sbuf + b + 64 + 4 * lane);

  // within-lane suffix scan of a0
  float s3 = a0.w;
  float s2 = OPF(a0.z, s3);
  float s1 = OPF(a0.y, s2);
  float s0 = OPF(a0.x, s1);
  // row-level inclusive suffix scan of lane totals (row_shl:d = lane i <- i+d)
  float t = s0;
  t = OPF(t, dpp_self<0x101>(t));
  t = OPF(t, dpp_self<0x102>(t));
  t = OPF(t, dpp_self<0x104>(t));
  t = OPF(t, dpp_self<0x108>(t));
  float E = dpp_old<0x101>(ID, t);   // exclusive lane-suffix (lane15 -> ID)

  // within-lane prefix scan of a1
  float p0 = a1.x;
  float p1 = OPF(p0, a1.y);
  float p2 = OPF(p1, a1.z);
  float p3 = OPF(p2, a1.w);
  float u = p3;
  u = OPF(u, dpp_self<0x111>(u));    // row_shr:d = lane i <- i-d
  u = OPF(u, dpp_self<0x112>(u));
  u = OPF(u, dpp_self<0x114>(u));
  u = OPF(u, dpp_self<0x118>(u));
  float Ep = dpp_old<0x111>(ID, u);  // exclusive lane-prefix (lane0 -> ID)

  r[0] = OPF(OPF(s0, E), Ep);
  r[1] = OPF(OPF(s1, E), OPF(Ep, p0));
  r[2] = OPF(OPF(s2, E), OPF(Ep, p1));
  r[3] = OPF(OPF(s3, E), OPF(Ep, p2));
  u_out = u;
#undef OPF
}

__global__ __launch_bounds__(512)
void mmh_kernel(const float* __restrict__ x,
                const float* __restrict__ prev_input,
                const float* __restrict__ prev_max_out,
                float* __restrict__ out)
{
    __shared__ float s_in[SLEN];    // pad[p] at s_in[p]:  [prev_input(63), x(4096)]
    __shared__ float s_mid[SLEN];   // mpad[p] at s_mid[p]: [prev_max_out(63), mid(4096)]

    const int row  = blockIdx.x;
    const int tid  = threadIdx.x;
    const int lane = tid & 63;
    const int wave = tid >> 6;      // 0..7

    const float* xrow  = x            + (size_t)row * TT;
    const float* pirow = prev_input   + (size_t)row * PADN;
    const float* pmrow = prev_max_out + (size_t)row * PADN;
    float*       orow  = out          + (size_t)row * TT;

    // ---- staging: x lands at s_in[63..4158]; realign to 16B in-register
    // (aligned float4 + 1 scalar -> shifted aligned b128 LDS write).
    for (int i = tid; i < 1023; i += 512) {
        float4 v = *reinterpret_cast<const float4*>(xrow + 4 * i);
        float  e = xrow[4 * i + 4];
        float4 w = make_float4(v.y, v.z, v.w, e);
        *reinterpret_cast<float4*>(&s_in[64 + 4 * i]) = w;   // = x[1+4i .. 4+4i]
    }
    if (tid < 63)       { s_in[tid] = pirow[tid]; s_mid[tid] = pmrow[tid]; }
    else if (tid == 63) { s_in[63] = xrow[0]; }
    else if (tid < 67)  { s_in[4156 + tid - 64] = xrow[4093 + tid - 64]; }
    else if (tid == 67) { s_in[4159] = -INFINITY; }
    else if (tid == 68) { s_mid[4159] = INFINITY; }
    __syncthreads();

    // ---- stage 1: sliding max over pad -> s_mid[63 + t] = mid[t] ----
    #pragma unroll
    for (int cc = 0; cc < 2; ++cc) {
        const int b = (wave + 8 * cc) << 8;
        float r[4], u;
        chunk_windows<true>(s_in, b, lane, r, u);
        // aligned b128 write of mid[1+b+4*lane .. 4+b+4*lane]; w3 = next
        // lane's r0 (row_shl:1); at l2==15 the needed value == a1-slab total == u.
        float  w3 = dpp_old<0x101>(u, r[0]);
        float4 wv = make_float4(r[1], r[2], r[3], w3);
        *reinterpret_cast<float4*>(&s_mid[64 + b + 4 * lane]) = wv;
        if ((b | lane) == 0) s_mid[63] = r[0];   // mid[0]
    }
    __syncthreads();

    // ---- stage 2: sliding min over mpad -> out (aligned global float4) ----
    #pragma unroll
    for (int cc = 0; cc < 2; ++cc) {
        const int b = (wave + 8 * cc) << 8;
        float r[4], u;
        chunk_windows<false>(s_mid, b, lane, r, u);
        *reinterpret_cast<float4*>(orow + b + 4 * lane) =
            make_float4(r[0], r[1], r[2], r[3]);
    }
}

extern "C" void kernel_launch(void* const* d_in, const int* in_sizes, int n_in,
                              void* d_out, int out_size, void* d_ws, size_t ws_size,
                              hipStream_t stream) {
    const float* x            = (const float*)d_in[0];  // [64,64,4096]
    const float* prev_input   = (const float*)d_in[1];  // [64,64,63]
    const float* prev_max_out = (const float*)d_in[2];  // [64,64,63]
    float*       out          = (float*)d_out;          // [64,64,4096]

    mmh_kernel<<<64 * 64, 512, 0, stream>>>(x, prev_input, prev_max_out, out);
}